// Round 4
// baseline (329.107 us; speedup 1.0000x reference)
//
#include <hip/hip_runtime.h>
#include <hip/hip_bf16.h>
#include <math.h>

// Problem constants
#define NCLS   19
#define KPC    100
#define NA     1900       // anchors (also first NA contrast cols)
#define NM     20000      // memory rows
#define NC     21900      // contrast rows = NA + NM
#define NCP2   22016      // contrast cols padded to multiple of 128
#define D      256        // feature dim
#define HW     16384      // 128*128
#define NPIX   131072     // 8*128*128
#define NT_M   15         // 1920/128 m-tiles
#define NT_N   172        // 22016/128 n-tiles

typedef __attribute__((ext_vector_type(8))) short bf16x8;
typedef __attribute__((ext_vector_type(4))) float f32x4;

// workspace byte offsets
#define WS_IDX   0         // 1900 ints
#define WS_ROWS  7680      // 1920 f
#define WS_ROWP  15360     // 1920 f
#define WS_HIST  23040     // 19 ints
#define WS_TKT   23168     // 1 int
#define WS_CLAB  23296     // 22016 ints
#define WS_CT2   111616    // bf16 [32 kq][22016 n][8] = 11,272,192 B

__device__ __forceinline__ short f2bf(float x) {
    __hip_bfloat16 h = __float2bfloat16(x);
    return *(short*)&h;
}

// ---------------- K0: memory normalize + labels + zeros + histogram ----------------
__global__ void prep_kernel(const float* __restrict__ mem, const int* __restrict__ memlab,
                            float* rowS, float* rowP, int* clab, int* hist, int* ticket,
                            short* __restrict__ Ct2) {
    const int b = blockIdx.x, t = threadIdx.x;
    if (b < 2500) {                       // normalize memory rows -> Ct2 cols NA..NC
        const int r = b * 8 + (t >> 5);
        const int kq = t & 31;
        const float4 v0 = *(const float4*)(mem + (size_t)r * D + kq * 8);
        const float4 v1 = *(const float4*)(mem + (size_t)r * D + kq * 8 + 4);
        float ssq = v0.x*v0.x + v0.y*v0.y + v0.z*v0.z + v0.w*v0.w
                  + v1.x*v1.x + v1.y*v1.y + v1.z*v1.z + v1.w*v1.w;
        #pragma unroll
        for (int o = 16; o; o >>= 1) ssq += __shfl_xor(ssq, o, 32);
        const float inv = 1.0f / fmaxf(sqrtf(ssq), 1e-12f);
        bf16x8 outv;
        outv[0] = f2bf(v0.x * inv); outv[1] = f2bf(v0.y * inv);
        outv[2] = f2bf(v0.z * inv); outv[3] = f2bf(v0.w * inv);
        outv[4] = f2bf(v1.x * inv); outv[5] = f2bf(v1.y * inv);
        outv[6] = f2bf(v1.z * inv); outv[7] = f2bf(v1.w * inv);
        *(bf16x8*)(Ct2 + ((size_t)kq * NCP2 + NA + r) * 8) = outv;
    } else if (b < 2586) {                // labels + zero accumulators + zero pad cols
        const int i = (b - 2500) * 256 + t;     // 0..22015
        clab[i] = (i < NA) ? ((i * 5243) >> 19)
                           : ((i < NC) ? memlab[i - NA] : -1);
        if (i < 1920) { rowS[i] = 0.f; rowP[i] = 0.f; }
        if (i < 32 * (NCP2 - NC)) {
            const int kq = i / (NCP2 - NC);
            const int n  = NC + (i - kq * (NCP2 - NC));
            bf16x8 z = {};
            *(bf16x8*)(Ct2 + ((size_t)kq * NCP2 + n) * 8) = z;
        }
    } else {                              // b==2586: class histogram + ticket
        __shared__ int h[NCLS];
        if (t < NCLS) h[t] = 0;
        if (t == 32) *ticket = 0;
        __syncthreads();
        for (int i = t; i < NM; i += 256) atomicAdd(&h[memlab[i]], 1);
        __syncthreads();
        if (t < NCLS) hist[t] = h[t];
    }
}

// ---------------- K1: first-K-per-class sampler (ascending order) ----------------
__global__ void sample_kernel(const int* __restrict__ labels, int* __restrict__ idx) {
    const int c = blockIdx.x;
    const int t = threadIdx.x;
    const int wave = t >> 6, lane = t & 63;
    __shared__ int s_base;
    __shared__ int s_wavecnt[4];
    if (t == 0) s_base = 0;
    __syncthreads();
    for (int start = 0; start < NPIX; start += 256) {
        const int i = start + t;
        const bool pred = (labels[i] == c);
        const unsigned long long b = __ballot(pred);
        if (lane == 0) s_wavecnt[wave] = __popcll(b);
        __syncthreads();
        const int base = s_base;
        int wbase = 0;
        for (int w = 0; w < wave; ++w) wbase += s_wavecnt[w];
        const int chunk_total = s_wavecnt[0] + s_wavecnt[1] + s_wavecnt[2] + s_wavecnt[3];
        if (pred) {
            const int rank = base + wbase + __popcll(b & ((1ULL << lane) - 1ULL));
            if (rank < KPC) idx[c * KPC + rank] = i;
        }
        __syncthreads();
        if (t == 0) s_base = base + chunk_total;
        if (base + chunk_total >= KPC) break;
    }
}

// ---------------- K2: gather + normalize anchors -> Ct2 cols 0..1899 ----------------
__global__ void anchor_kernel(const float* __restrict__ pixel, const int* __restrict__ idx,
                              short* __restrict__ Ct2) {
    const int t = threadIdx.x;
    const int a = blockIdx.x * 8 + (t >> 5);
    const int kq = t & 31;
    if (a >= NA) return;
    const int p = idx[a];
    const int b = p >> 14;
    const int hw = p & (HW - 1);
    const float* base = pixel + ((size_t)(b * D + kq * 8)) * HW + hw;
    float v[8];
    float ssq = 0.f;
    #pragma unroll
    for (int j = 0; j < 8; ++j) { v[j] = base[(size_t)j * HW]; ssq += v[j] * v[j]; }
    #pragma unroll
    for (int o = 16; o; o >>= 1) ssq += __shfl_xor(ssq, o, 32);
    const float inv = 1.0f / fmaxf(sqrtf(ssq), 1e-12f);
    bf16x8 outv;
    #pragma unroll
    for (int j = 0; j < 8; ++j) outv[j] = f2bf(v[j] * inv);
    *(bf16x8*)(Ct2 + ((size_t)kq * NCP2 + a) * 8) = outv;
}

// ---------------- K3: barrier-free direct-to-VGPR MFMA GEMM + fused epilogue ----------------
// No LDS, no __syncthreads in the hot loop. Each wave owns a 64x64 tile; A/B
// fragments are single contiguous 16B global loads (layout [kq][n][8]), register
// double-buffered across the 8-step K loop. 2x2 waves/block share strips via L1/L2.
__global__ __launch_bounds__(256, 3)
void gemm_kernel(const short* __restrict__ Ct2, const int* __restrict__ clab,
                 float* __restrict__ rowS, float* __restrict__ rowP,
                 const int* __restrict__ hist, int* ticket, float* __restrict__ out) {
    const int tid  = threadIdx.x;
    const int lane = tid & 63;
    const int w    = tid >> 6;
    const int wm   = w >> 1, wn = w & 1;
    const int quad = lane >> 4;
    const int l16  = lane & 15;
    const int m0   = blockIdx.x * 128 + wm * 64;
    const int n0   = blockIdx.y * 128 + wn * 64;

    const short* pa = Ct2 + ((size_t)quad * NCP2 + m0 + l16) * 8;
    const short* pb = Ct2 + ((size_t)quad * NCP2 + n0 + l16) * 8;
    const size_t KSS = (size_t)4 * NCP2 * 8;   // shorts per 32-dim k step

    bf16x8 a[2][4], b[2][4];
    #pragma unroll
    for (int mi = 0; mi < 4; ++mi) {
        a[0][mi] = *(const bf16x8*)(pa + mi * 128);
        b[0][mi] = *(const bf16x8*)(pb + mi * 128);
    }
    f32x4 acc[4][4] = {};

    #pragma unroll
    for (int ks = 0; ks < 8; ++ks) {
        const int cur = ks & 1, nxt = cur ^ 1;
        if (ks < 7) {
            const size_t off = (size_t)(ks + 1) * KSS;
            #pragma unroll
            for (int mi = 0; mi < 4; ++mi) {
                a[nxt][mi] = *(const bf16x8*)(pa + off + mi * 128);
                b[nxt][mi] = *(const bf16x8*)(pb + off + mi * 128);
            }
        }
        #pragma unroll
        for (int mi = 0; mi < 4; ++mi)
            #pragma unroll
            for (int ni = 0; ni < 4; ++ni)
                acc[mi][ni] = __builtin_amdgcn_mfma_f32_16x16x32_bf16(
                    a[cur][mi], b[cur][ni], acc[mi][ni], 0, 0, 0);
    }

    // fused epilogue: per-row exp-sum and same-class logit-sum, one atomic pair/row
    int nLab[4];
    #pragma unroll
    for (int ni = 0; ni < 4; ++ni) {
        const int n = n0 + ni * 16 + l16;
        nLab[ni] = (n < NC) ? clab[n] : -1;
    }
    #pragma unroll
    for (int mi = 0; mi < 4; ++mi) {
        #pragma unroll
        for (int r = 0; r < 4; ++r) {
            const int m = m0 + mi * 16 + quad * 4 + r;     // C/D: row=(lane>>4)*4+reg
            const int mlab = (m * 5243) >> 19;             // m/100
            float s = 0.f, p = 0.f;
            #pragma unroll
            for (int ni = 0; ni < 4; ++ni) {
                const int n = n0 + ni * 16 + l16;
                if (n < NC && n != m) {
                    const float l = acc[mi][ni][r] * 10.0f;
                    s += __expf(l);
                    if (nLab[ni] == mlab) p += l;
                }
            }
            #pragma unroll
            for (int o = 1; o < 16; o <<= 1) {             // reduce over l16 within quad
                s += __shfl_xor(s, o, 64);
                p += __shfl_xor(p, o, 64);
            }
            if (l16 == 0 && m < NA) {
                atomicAdd(&rowS[m], s);
                atomicAdd(&rowP[m], p);
            }
        }
    }

    // ---- fused finalize: last block computes the loss ----
    __shared__ int flag;
    __shared__ float rs[4];
    __syncthreads();
    if (tid == 0) {
        __threadfence();
        flag = (atomicAdd(ticket, 1) == NT_M * NT_N - 1) ? 1 : 0;
    }
    __syncthreads();
    if (flag) {
        __threadfence();
        float sum = 0.f;
        for (int n = tid; n < NA; n += 256) {
            const int cls = (n * 5243) >> 19;
            const float cnt = 99.0f + (float)hist[cls];
            const float logS = logf(rowS[n] + 1e-12f);
            sum += (rowP[n] - cnt * logS) / cnt;
        }
        #pragma unroll
        for (int o = 32; o; o >>= 1) sum += __shfl_xor(sum, o, 64);
        if (lane == 0) rs[w] = sum;
        __syncthreads();
        if (tid == 0) out[0] = -(10.0f / 7.0f) * ((rs[0] + rs[1] + rs[2] + rs[3]) / 1900.0f);
    }
}

extern "C" void kernel_launch(void* const* d_in, const int* in_sizes, int n_in,
                              void* d_out, int out_size, void* d_ws, size_t ws_size,
                              hipStream_t stream) {
    const float* pixel  = (const float*)d_in[0];   // [8,256,128,128]
    const int*   labels = (const int*)d_in[1];     // [8,128,128]
    const float* mem    = (const float*)d_in[2];   // [20000,256]
    const int*   memlab = (const int*)d_in[3];     // [20000]
    char* ws = (char*)d_ws;
    int*   idx  = (int*)(ws + WS_IDX);
    float* rowS = (float*)(ws + WS_ROWS);
    float* rowP = (float*)(ws + WS_ROWP);
    int*   hist = (int*)(ws + WS_HIST);
    int*   tkt  = (int*)(ws + WS_TKT);
    int*   clab = (int*)(ws + WS_CLAB);
    short* Ct2  = (short*)(ws + WS_CT2);
    float* out  = (float*)d_out;

    prep_kernel<<<dim3(2587), dim3(256), 0, stream>>>(mem, memlab, rowS, rowP, clab, hist, tkt, Ct2);
    sample_kernel<<<dim3(NCLS), dim3(256), 0, stream>>>(labels, idx);
    anchor_kernel<<<dim3(238), dim3(256), 0, stream>>>(pixel, idx, Ct2);
    gemm_kernel<<<dim3(NT_M, NT_N), dim3(256), 0, stream>>>(Ct2, clab, rowS, rowP, hist, tkt, out);
}

// Round 5
// 299.343 us; speedup vs baseline: 1.0994x; 1.0994x over previous
//
#include <hip/hip_runtime.h>
#include <hip/hip_bf16.h>
#include <math.h>

// Problem constants
#define NCLS   19
#define KPC    100
#define NA     1900       // anchors (also first NA contrast cols)
#define NM     20000      // memory rows
#define NC     21900      // contrast rows = NA + NM
#define NCP2   22016      // contrast cols padded to multiple of 128
#define D      256        // feature dim
#define HW     16384      // 128*128
#define NPIX   131072     // 8*128*128
#define NBLK   688        // 172 n-strips x 4 m-groups

typedef __attribute__((ext_vector_type(8))) short bf16x8;
typedef __attribute__((ext_vector_type(4))) float f32x4;

// workspace byte offsets
#define WS_IDX   0         // 1900 ints
#define WS_ROWS  7680      // 1920 f
#define WS_ROWP  15360     // 1920 f
#define WS_HIST  23040     // 19 ints
#define WS_TKT   23168     // 1 int
#define WS_CLAB  23296     // 22016 ints
#define WS_CT2   111616    // bf16 [32 kq][22016 n][8] = 11,272,192 B

__device__ __forceinline__ short f2bf(float x) {
    __hip_bfloat16 h = __float2bfloat16(x);
    return *(short*)&h;
}

// ---------------- K0: memory normalize + labels + zeros + histogram ----------------
__global__ void prep_kernel(const float* __restrict__ mem, const int* __restrict__ memlab,
                            float* rowS, float* rowP, int* clab, int* hist, int* ticket,
                            short* __restrict__ Ct2) {
    const int b = blockIdx.x, t = threadIdx.x;
    if (b < 2500) {                       // normalize memory rows -> Ct2 cols NA..NC
        const int r = b * 8 + (t >> 5);
        const int kq = t & 31;
        const float4 v0 = *(const float4*)(mem + (size_t)r * D + kq * 8);
        const float4 v1 = *(const float4*)(mem + (size_t)r * D + kq * 8 + 4);
        float ssq = v0.x*v0.x + v0.y*v0.y + v0.z*v0.z + v0.w*v0.w
                  + v1.x*v1.x + v1.y*v1.y + v1.z*v1.z + v1.w*v1.w;
        #pragma unroll
        for (int o = 16; o; o >>= 1) ssq += __shfl_xor(ssq, o, 32);
        const float inv = 1.0f / fmaxf(sqrtf(ssq), 1e-12f);
        bf16x8 outv;
        outv[0] = f2bf(v0.x * inv); outv[1] = f2bf(v0.y * inv);
        outv[2] = f2bf(v0.z * inv); outv[3] = f2bf(v0.w * inv);
        outv[4] = f2bf(v1.x * inv); outv[5] = f2bf(v1.y * inv);
        outv[6] = f2bf(v1.z * inv); outv[7] = f2bf(v1.w * inv);
        *(bf16x8*)(Ct2 + ((size_t)kq * NCP2 + NA + r) * 8) = outv;
    } else if (b < 2586) {                // labels + zero accumulators + zero pad cols
        const int i = (b - 2500) * 256 + t;     // 0..22015
        clab[i] = (i < NA) ? ((i * 5243) >> 19)
                           : ((i < NC) ? memlab[i - NA] : -1);
        if (i < 1920) { rowS[i] = 0.f; rowP[i] = 0.f; }
        if (i < 32 * (NCP2 - NC)) {
            const int kq = i / (NCP2 - NC);
            const int n  = NC + (i - kq * (NCP2 - NC));
            bf16x8 z = {};
            *(bf16x8*)(Ct2 + ((size_t)kq * NCP2 + n) * 8) = z;
        }
    } else {                              // b==2586: class histogram + ticket
        __shared__ int h[NCLS];
        if (t < NCLS) h[t] = 0;
        if (t == 32) *ticket = 0;
        __syncthreads();
        for (int i = t; i < NM; i += 256) atomicAdd(&h[memlab[i]], 1);
        __syncthreads();
        if (t < NCLS) hist[t] = h[t];
    }
}

// ---------------- K1: first-K-per-class sampler (ascending order) ----------------
__global__ void sample_kernel(const int* __restrict__ labels, int* __restrict__ idx) {
    const int c = blockIdx.x;
    const int t = threadIdx.x;
    const int wave = t >> 6, lane = t & 63;
    __shared__ int s_base;
    __shared__ int s_wavecnt[4];
    if (t == 0) s_base = 0;
    __syncthreads();
    for (int start = 0; start < NPIX; start += 256) {
        const int i = start + t;
        const bool pred = (labels[i] == c);
        const unsigned long long b = __ballot(pred);
        if (lane == 0) s_wavecnt[wave] = __popcll(b);
        __syncthreads();
        const int base = s_base;
        int wbase = 0;
        for (int w = 0; w < wave; ++w) wbase += s_wavecnt[w];
        const int chunk_total = s_wavecnt[0] + s_wavecnt[1] + s_wavecnt[2] + s_wavecnt[3];
        if (pred) {
            const int rank = base + wbase + __popcll(b & ((1ULL << lane) - 1ULL));
            if (rank < KPC) idx[c * KPC + rank] = i;
        }
        __syncthreads();
        if (t == 0) s_base = base + chunk_total;
        if (base + chunk_total >= KPC) break;
    }
}

// ---------------- K2: gather + normalize anchors -> Ct2 cols 0..1899 ----------------
__global__ void anchor_kernel(const float* __restrict__ pixel, const int* __restrict__ idx,
                              short* __restrict__ Ct2) {
    const int t = threadIdx.x;
    const int a = blockIdx.x * 8 + (t >> 5);
    const int kq = t & 31;
    if (a >= NA) return;
    const int p = idx[a];
    const int b = p >> 14;
    const int hw = p & (HW - 1);
    const float* base = pixel + ((size_t)(b * D + kq * 8)) * HW + hw;
    float v[8];
    float ssq = 0.f;
    #pragma unroll
    for (int j = 0; j < 8; ++j) { v[j] = base[(size_t)j * HW]; ssq += v[j] * v[j]; }
    #pragma unroll
    for (int o = 16; o; o >>= 1) ssq += __shfl_xor(ssq, o, 32);
    const float inv = 1.0f / fmaxf(sqrtf(ssq), 1e-12f);
    bf16x8 outv;
    #pragma unroll
    for (int j = 0; j < 8; ++j) outv[j] = f2bf(v[j] * inv);
    *(bf16x8*)(Ct2 + ((size_t)kq * NCP2 + a) * 8) = outv;
}

// ---------------- K3: contrast-stationary MFMA GEMM, barrier-free m-loop ----------------
// Block: 128-col contrast strip full-K resident in 64KB LDS (1 barrier total).
// Anchors stream from global (L2-hot, 1MB) as MFMA-B-operand, 2-iter register
// prefetch. Operand order: contrast=first => C/D col = m => softmax-sum over n
// is IN-LANE; per-slice epilogue is only 16 shfl + 8 atomics per wave.
__global__ __launch_bounds__(256, 2)
void gemm_kernel(const short* __restrict__ Ct2, const int* __restrict__ clab,
                 float* __restrict__ rowS, float* __restrict__ rowP,
                 const int* __restrict__ hist, int* ticket, float* __restrict__ out) {
    __shared__ __align__(16) short Ls[32768];   // 64 KB: [32 kq][128 n][8]
    const int tid  = threadIdx.x;
    const int lane = tid & 63;
    const int w    = tid >> 6;
    const int wm   = w >> 1;      // anchor 64-half within slice
    const int wn   = w & 1;       // contrast 64-half within strip
    const int quad = lane >> 4, l16 = lane & 15;
    const int g    = blockIdx.x;  // n-strip 0..171
    const int mg   = blockIdx.y;  // m-group 0..3
    const int n0   = g * 128;
    const int s0   = mg * 4;                  // first 128-row anchor slice
    const int NS   = (mg < 3) ? 4 : 3;        // group 3 has slices 12..14
    const int Q    = NS * 8;                  // k-steps total

    // ---- stage contrast strip (64 KB), once ----
    #pragma unroll
    for (int i = 0; i < 16; ++i) {
        const int c  = w * 16 + i;            // 0..63
        const int kq = c >> 1;
        const int nl = (c & 1) * 64;
        __builtin_amdgcn_global_load_lds(
            (const __attribute__((address_space(1))) void*)(Ct2 + ((size_t)kq * NCP2 + n0 + nl + lane) * 8),
            (__attribute__((address_space(3))) void*)(Ls + (size_t)(kq * 128 + nl + lane) * 8),
            16, 0, 0);
    }
    __syncthreads();                          // the only barrier before finalize

    // per-lane contrast labels (fixed for whole block)
    const int nbase = n0 + wn * 64 + quad * 4;        // + ni*16 + j
    int labv[16];
    #pragma unroll
    for (int ni = 0; ni < 4; ++ni)
        #pragma unroll
        for (int j = 0; j < 4; ++j)
            labv[ni * 4 + j] = clab[nbase + ni * 16 + j];

#define APTR(q, ni) ((const bf16x8*)(Ls + (size_t)((((q) & 7) * 4 + quad) * 128 + wn * 64 + (ni) * 16 + l16) * 8))
#define BPTR(q, mi) ((const bf16x8*)(Ct2 + ((size_t)(((q) & 7) * 4 + quad) * NCP2 \
                        + (s0 + ((q) >> 3)) * 128 + wm * 64 + (mi) * 16 + l16) * 8))

    bf16x8 a0[4], a1[4], b0[4], b1[4];
    #pragma unroll
    for (int x = 0; x < 4; ++x) {
        a0[x] = *APTR(0, x);
        b0[x] = *BPTR(0, x);
        b1[x] = *BPTR(1, x);
    }
    f32x4 acc[4][4] = {};                     // [mi][ni]

    for (int qq = 0; qq < Q; qq += 2) {
        // ---- even step qq: consume (a0, b0) ----
        #pragma unroll
        for (int x = 0; x < 4; ++x) a1[x] = *APTR(qq + 1, x);
        #pragma unroll
        for (int ni = 0; ni < 4; ++ni)
            #pragma unroll
            for (int mi = 0; mi < 4; ++mi)
                acc[mi][ni] = __builtin_amdgcn_mfma_f32_16x16x32_bf16(
                    a0[ni], b0[mi], acc[mi][ni], 0, 0, 0);
        if (qq + 2 < Q) {
            #pragma unroll
            for (int x = 0; x < 4; ++x) b0[x] = *BPTR(qq + 2, x);
        }
        // ---- odd step qq+1: consume (a1, b1) ----
        #pragma unroll
        for (int x = 0; x < 4; ++x) a0[x] = *APTR(qq + 2, x);   // kc wraps via &7; always valid
        #pragma unroll
        for (int ni = 0; ni < 4; ++ni)
            #pragma unroll
            for (int mi = 0; mi < 4; ++mi)
                acc[mi][ni] = __builtin_amdgcn_mfma_f32_16x16x32_bf16(
                    a1[ni], b1[mi], acc[mi][ni], 0, 0, 0);
        if (qq + 3 < Q) {
            #pragma unroll
            for (int x = 0; x < 4; ++x) b1[x] = *BPTR(qq + 3, x);
        }
        // ---- slice boundary: fused epilogue (in-lane n-sums) ----
        if (((qq + 1) & 7) == 7) {
            const int mb = (s0 + ((qq + 1) >> 3)) * 128 + wm * 64;
            #pragma unroll
            for (int mi = 0; mi < 4; ++mi) {
                const int m    = mb + mi * 16 + l16;
                const int mlab = (m * 5243) >> 19;       // m/100 (>=19 for pad rows)
                const int dm   = nbase - m;              // n-m = dm + ni*16 + j
                float s = 0.f, p = 0.f;
                #pragma unroll
                for (int ni = 0; ni < 4; ++ni)
                    #pragma unroll
                    for (int j = 0; j < 4; ++j) {
                        const float l = acc[mi][ni][j] * 10.0f;
                        const int lv  = labv[ni * 4 + j];
                        const bool nd = (dm + ni * 16 + j) != 0;   // n != m
                        if (lv >= 0 && nd) s += __expf(l);         // lv<0 masks pad cols
                        if (lv == mlab && nd) p += l;
                    }
                s += __shfl_xor(s, 16, 64); s += __shfl_xor(s, 32, 64);
                p += __shfl_xor(p, 16, 64); p += __shfl_xor(p, 32, 64);
                if (quad == 0 && m < NA) {
                    atomicAdd(&rowS[m], s);
                    atomicAdd(&rowP[m], p);
                }
                acc[mi][0] = f32x4{}; acc[mi][1] = f32x4{};
                acc[mi][2] = f32x4{}; acc[mi][3] = f32x4{};
            }
        }
    }
#undef APTR
#undef BPTR

    // ---- fused finalize: last block computes the loss ----
    __syncthreads();
    int* flag  = (int*)Ls;
    float* rs  = (float*)(Ls + 64);
    if (tid == 0) {
        __threadfence();
        flag[0] = (atomicAdd(ticket, 1) == NBLK - 1) ? 1 : 0;
    }
    __syncthreads();
    if (flag[0]) {
        __threadfence();
        float sum = 0.f;
        for (int n = tid; n < NA; n += 256) {
            const int cls = (n * 5243) >> 19;
            const float cnt = 99.0f + (float)hist[cls];
            const float logS = logf(rowS[n] + 1e-12f);
            sum += (rowP[n] - cnt * logS) / cnt;
        }
        #pragma unroll
        for (int o = 32; o; o >>= 1) sum += __shfl_xor(sum, o, 64);
        if (lane == 0) rs[w] = sum;
        __syncthreads();
        if (tid == 0) out[0] = -(10.0f / 7.0f) * ((rs[0] + rs[1] + rs[2] + rs[3]) / 1900.0f);
    }
}

extern "C" void kernel_launch(void* const* d_in, const int* in_sizes, int n_in,
                              void* d_out, int out_size, void* d_ws, size_t ws_size,
                              hipStream_t stream) {
    const float* pixel  = (const float*)d_in[0];   // [8,256,128,128]
    const int*   labels = (const int*)d_in[1];     // [8,128,128]
    const float* mem    = (const float*)d_in[2];   // [20000,256]
    const int*   memlab = (const int*)d_in[3];     // [20000]
    char* ws = (char*)d_ws;
    int*   idx  = (int*)(ws + WS_IDX);
    float* rowS = (float*)(ws + WS_ROWS);
    float* rowP = (float*)(ws + WS_ROWP);
    int*   hist = (int*)(ws + WS_HIST);
    int*   tkt  = (int*)(ws + WS_TKT);
    int*   clab = (int*)(ws + WS_CLAB);
    short* Ct2  = (short*)(ws + WS_CT2);
    float* out  = (float*)d_out;

    prep_kernel<<<dim3(2587), dim3(256), 0, stream>>>(mem, memlab, rowS, rowP, clab, hist, tkt, Ct2);
    sample_kernel<<<dim3(NCLS), dim3(256), 0, stream>>>(labels, idx);
    anchor_kernel<<<dim3(238), dim3(256), 0, stream>>>(pixel, idx, Ct2);
    gemm_kernel<<<dim3(172, 4), dim3(256), 0, stream>>>(Ct2, clab, rowS, rowP, hist, tkt, out);
}

// Round 6
// 275.790 us; speedup vs baseline: 1.1933x; 1.0854x over previous
//
#include <hip/hip_runtime.h>
#include <hip/hip_bf16.h>
#include <math.h>

// Problem constants
#define NCLS   19
#define KPC    100
#define NA     1900       // anchors (also first NA contrast cols)
#define NM     20000      // memory rows
#define NC     21900      // contrast rows = NA + NM
#define NCP2   22016      // contrast cols padded to multiple of 128
#define D      256        // feature dim
#define HW     16384      // 128*128
#define NPIX   131072     // 8*128*128
#define NBLK   2640       // gemm grid: 8 xcd * 330 (15 m * 22 n), ~60 idle

typedef __attribute__((ext_vector_type(8))) short bf16x8;
typedef __attribute__((ext_vector_type(4))) float f32x4;

// workspace byte offsets
#define WS_IDX   0         // 1900 ints
#define WS_ROWS  7680      // 1920 f
#define WS_ROWP  15360     // 1920 f
#define WS_HIST  23040     // 19 ints
#define WS_TKT   23168     // 1 int
#define WS_CLAB  23296     // 22016 ints
#define WS_CT2   111616    // bf16 [32 kq][22016 n][8] = 11,272,192 B

__device__ __forceinline__ short f2bf(float x) {
    __hip_bfloat16 h = __float2bfloat16(x);
    return *(short*)&h;
}

// ---------------- K1: first-K-per-class sampler (ascending order) ----------------
__global__ void sample_kernel(const int* __restrict__ labels, int* __restrict__ idx) {
    const int c = blockIdx.x;
    const int t = threadIdx.x;
    const int wave = t >> 6, lane = t & 63;
    __shared__ int s_base;
    __shared__ int s_wavecnt[4];
    if (t == 0) s_base = 0;
    __syncthreads();
    for (int start = 0; start < NPIX; start += 256) {
        const int i = start + t;
        const bool pred = (labels[i] == c);
        const unsigned long long b = __ballot(pred);
        if (lane == 0) s_wavecnt[wave] = __popcll(b);
        __syncthreads();
        const int base = s_base;
        int wbase = 0;
        for (int w = 0; w < wave; ++w) wbase += s_wavecnt[w];
        const int chunk_total = s_wavecnt[0] + s_wavecnt[1] + s_wavecnt[2] + s_wavecnt[3];
        if (pred) {
            const int rank = base + wbase + __popcll(b & ((1ULL << lane) - 1ULL));
            if (rank < KPC) idx[c * KPC + rank] = i;
        }
        __syncthreads();
        if (t == 0) s_base = base + chunk_total;
        if (base + chunk_total >= KPC) break;
    }
}

// ---------------- K2: mega-prep: memory norm + labels/zeros + hist + anchor gather ----------------
__global__ void prep_kernel(const float* __restrict__ mem, const int* __restrict__ memlab,
                            const float* __restrict__ pixel, const int* __restrict__ idx,
                            float* rowS, float* rowP, int* clab, int* hist, int* ticket,
                            short* __restrict__ Ct2) {
    const int b = blockIdx.x, t = threadIdx.x;
    if (b < 2500) {                       // normalize memory rows -> Ct2 cols NA..NC
        const int r = b * 8 + (t >> 5);
        const int kq = t & 31;
        const float4 v0 = *(const float4*)(mem + (size_t)r * D + kq * 8);
        const float4 v1 = *(const float4*)(mem + (size_t)r * D + kq * 8 + 4);
        float ssq = v0.x*v0.x + v0.y*v0.y + v0.z*v0.z + v0.w*v0.w
                  + v1.x*v1.x + v1.y*v1.y + v1.z*v1.z + v1.w*v1.w;
        #pragma unroll
        for (int o = 16; o; o >>= 1) ssq += __shfl_xor(ssq, o, 32);
        const float inv = 1.0f / fmaxf(sqrtf(ssq), 1e-12f);
        bf16x8 outv;
        outv[0] = f2bf(v0.x * inv); outv[1] = f2bf(v0.y * inv);
        outv[2] = f2bf(v0.z * inv); outv[3] = f2bf(v0.w * inv);
        outv[4] = f2bf(v1.x * inv); outv[5] = f2bf(v1.y * inv);
        outv[6] = f2bf(v1.z * inv); outv[7] = f2bf(v1.w * inv);
        *(bf16x8*)(Ct2 + ((size_t)kq * NCP2 + NA + r) * 8) = outv;
    } else if (b < 2586) {                // labels + zero accumulators + zero pad cols
        const int i = (b - 2500) * 256 + t;     // 0..22015
        clab[i] = (i < NA) ? ((i * 5243) >> 19)
                           : ((i < NC) ? memlab[i - NA] : -1);
        if (i < 1920) { rowS[i] = 0.f; rowP[i] = 0.f; }
        if (i < 32 * (NCP2 - NC)) {
            const int kq = i / (NCP2 - NC);
            const int n  = NC + (i - kq * (NCP2 - NC));
            bf16x8 z = {};
            *(bf16x8*)(Ct2 + ((size_t)kq * NCP2 + n) * 8) = z;
        }
    } else if (b == 2586) {               // class histogram + ticket reset
        __shared__ int h[NCLS];
        if (t < NCLS) h[t] = 0;
        if (t == 32) *ticket = 0;
        __syncthreads();
        for (int i = t; i < NM; i += 256) atomicAdd(&h[memlab[i]], 1);
        __syncthreads();
        if (t < NCLS) hist[t] = h[t];
    } else {                              // anchor gather + normalize -> Ct2 cols 0..1899
        const int a = (b - 2587) * 8 + (t >> 5);
        const int kq = t & 31;
        if (a >= NA) return;
        const int p = idx[a];
        const int bb = p >> 14;
        const int hw = p & (HW - 1);
        const float* base = pixel + ((size_t)(bb * D + kq * 8)) * HW + hw;
        float v[8];
        float ssq = 0.f;
        #pragma unroll
        for (int jj = 0; jj < 8; ++jj) { v[jj] = base[(size_t)jj * HW]; ssq += v[jj] * v[jj]; }
        #pragma unroll
        for (int o = 16; o; o >>= 1) ssq += __shfl_xor(ssq, o, 32);
        const float inv = 1.0f / fmaxf(sqrtf(ssq), 1e-12f);
        bf16x8 outv;
        #pragma unroll
        for (int jj = 0; jj < 8; ++jj) outv[jj] = f2bf(v[jj] * inv);
        *(bf16x8*)(Ct2 + ((size_t)kq * NCP2 + a) * 8) = outv;
    }
}

// ---------------- K3: m97-skeleton MFMA GEMM, XCD-partitioned, in-lane epilogue ----------------
// 128x128 tile, single-buffered 32KB LDS, 2-barrier K-chunks (BK=64, 4 chunks),
// 3 blocks/CU. Operand order: contrast=first => C/D col=m, row=n => softmax sums
// over n are in-lane + 2 quad-shfls. Grid linear, blk%8 partitions n-strips per
// XCD so each XCD's L2 holds its 2.4MB working set.
__global__ __launch_bounds__(256, 3)
void gemm_kernel(const short* __restrict__ Ct2, const int* __restrict__ clab,
                 float* __restrict__ rowS, float* __restrict__ rowP,
                 const int* __restrict__ hist, int* ticket, float* __restrict__ out) {
    __shared__ __align__(16) short As[8 * 128 * 8];   // contrast chunk, 16 KB
    __shared__ __align__(16) short Bs[8 * 128 * 8];   // anchor chunk, 16 KB
    __shared__ int flag;
    __shared__ float rs[4];
    const int tid  = threadIdx.x;
    const int lane = tid & 63;
    const int w    = tid >> 6;
    const int wn   = w >> 1, wm = w & 1;
    const int quad = lane >> 4, l16 = lane & 15;

    const int L   = blockIdx.x;
    const int xcd = L & 7;
    const int j   = L >> 3;               // 0..329
    const int m_t = j % 15;
    const int nl  = j / 15;               // 0..21
    const int cnt = (xcd < 4) ? 22 : 21;
    const int nst = (xcd < 4) ? xcd * 22 : 88 + (xcd - 4) * 21;

    if (nl < cnt) {
        const int m0 = m_t * 128;
        const int n0 = (nst + nl) * 128;
        f32x4 acc[4][4] = {};             // [mi][ni]

        for (int kc = 0; kc < 4; ++kc) {
            #pragma unroll
            for (int i = 0; i < 4; ++i) {
                const int c    = w * 4 + i;        // 0..15
                const int kq   = c >> 1;
                const int half = (c & 1) * 64;
                const int kqg  = kc * 8 + kq;
                __builtin_amdgcn_global_load_lds(
                    (const __attribute__((address_space(1))) void*)(Ct2 + ((size_t)kqg * NCP2 + n0 + half + lane) * 8),
                    (__attribute__((address_space(3))) void*)(As + (size_t)(kq * 128 + half + lane) * 8),
                    16, 0, 0);
                __builtin_amdgcn_global_load_lds(
                    (const __attribute__((address_space(1))) void*)(Ct2 + ((size_t)kqg * NCP2 + m0 + half + lane) * 8),
                    (__attribute__((address_space(3))) void*)(Bs + (size_t)(kq * 128 + half + lane) * 8),
                    16, 0, 0);
            }
            __syncthreads();
            #pragma unroll
            for (int ks = 0; ks < 2; ++ks) {
                const int kqb = ks * 4 + quad;
                bf16x8 af[4], bfm[4];
                #pragma unroll
                for (int ni = 0; ni < 4; ++ni)
                    af[ni] = *(const bf16x8*)(As + (size_t)(kqb * 128 + wn * 64 + ni * 16 + l16) * 8);
                #pragma unroll
                for (int mi = 0; mi < 4; ++mi)
                    bfm[mi] = *(const bf16x8*)(Bs + (size_t)(kqb * 128 + wm * 64 + mi * 16 + l16) * 8);
                #pragma unroll
                for (int mi = 0; mi < 4; ++mi)
                    #pragma unroll
                    for (int ni = 0; ni < 4; ++ni)
                        acc[mi][ni] = __builtin_amdgcn_mfma_f32_16x16x32_bf16(
                            af[ni], bfm[mi], acc[mi][ni], 0, 0, 0);
            }
            __syncthreads();
        }

        // in-lane epilogue: n = n0+wn*64+ni*16+quad*4+r (row), m = m0+wm*64+mi*16+l16 (col)
        const int nbase = n0 + wn * 64 + quad * 4;
        int labv[16];
        #pragma unroll
        for (int ni = 0; ni < 4; ++ni)
            #pragma unroll
            for (int r = 0; r < 4; ++r)
                labv[ni * 4 + r] = clab[nbase + ni * 16 + r];
        #pragma unroll
        for (int mi = 0; mi < 4; ++mi) {
            const int m    = m0 + wm * 64 + mi * 16 + l16;
            const int mlab = (m * 5243) >> 19;     // m/100; >=19 for pad rows -> never matches
            float s = 0.f, p = 0.f;
            #pragma unroll
            for (int ni = 0; ni < 4; ++ni)
                #pragma unroll
                for (int r = 0; r < 4; ++r) {
                    const int n  = nbase + ni * 16 + r;
                    const int lv = labv[ni * 4 + r];
                    const float l = acc[mi][ni][r] * 10.0f;
                    if (lv >= 0 && n != m) {       // lv<0 masks tail pad cols
                        s += __expf(l);
                        if (lv == mlab) p += l;
                    }
                }
            s += __shfl_xor(s, 16, 64); s += __shfl_xor(s, 32, 64);
            p += __shfl_xor(p, 16, 64); p += __shfl_xor(p, 32, 64);
            if (quad == 0 && m < NA) {
                atomicAdd(&rowS[m], s);
                atomicAdd(&rowP[m], p);
            }
        }
    }

    // ---- fused finalize: last of NBLK blocks computes the loss ----
    __syncthreads();
    if (tid == 0) {
        __threadfence();
        flag = (atomicAdd(ticket, 1) == NBLK - 1) ? 1 : 0;
    }
    __syncthreads();
    if (flag) {
        __threadfence();
        float sum = 0.f;
        for (int n = tid; n < NA; n += 256) {
            const int cls = (n * 5243) >> 19;
            const float cntf = 99.0f + (float)hist[cls];
            const float logS = logf(rowS[n] + 1e-12f);
            sum += (rowP[n] - cntf * logS) / cntf;
        }
        #pragma unroll
        for (int o = 32; o; o >>= 1) sum += __shfl_xor(sum, o, 64);
        if (lane == 0) rs[w] = sum;
        __syncthreads();
        if (tid == 0) out[0] = -(10.0f / 7.0f) * ((rs[0] + rs[1] + rs[2] + rs[3]) / 1900.0f);
    }
}

extern "C" void kernel_launch(void* const* d_in, const int* in_sizes, int n_in,
                              void* d_out, int out_size, void* d_ws, size_t ws_size,
                              hipStream_t stream) {
    const float* pixel  = (const float*)d_in[0];   // [8,256,128,128]
    const int*   labels = (const int*)d_in[1];     // [8,128,128]
    const float* mem    = (const float*)d_in[2];   // [20000,256]
    const int*   memlab = (const int*)d_in[3];     // [20000]
    char* ws = (char*)d_ws;
    int*   idx  = (int*)(ws + WS_IDX);
    float* rowS = (float*)(ws + WS_ROWS);
    float* rowP = (float*)(ws + WS_ROWP);
    int*   hist = (int*)(ws + WS_HIST);
    int*   tkt  = (int*)(ws + WS_TKT);
    int*   clab = (int*)(ws + WS_CLAB);
    short* Ct2  = (short*)(ws + WS_CT2);
    float* out  = (float*)d_out;

    sample_kernel<<<dim3(NCLS), dim3(256), 0, stream>>>(labels, idx);
    prep_kernel<<<dim3(2825), dim3(256), 0, stream>>>(mem, memlab, pixel, idx,
                                                      rowS, rowP, clab, hist, tkt, Ct2);
    gemm_kernel<<<dim3(NBLK), dim3(256), 0, stream>>>(Ct2, clab, rowS, rowP, hist, tkt, out);
}